// Round 4
// baseline (467.014 us; speedup 1.0000x reference)
//
#include <hip/hip_runtime.h>
#include <hip/hip_bf16.h>

typedef unsigned short u16;
typedef unsigned int u32;
typedef short short8 __attribute__((ext_vector_type(8)));
typedef float f32x4 __attribute__((ext_vector_type(4)));

constexpr int BATCH = 32, L = 200, NUM_C = 256, NUM_D = 32, V = 128;
constexpr int G3 = 384;                 // 3*V
constexpr int KQ = 512;                 // Q row: 384 gx | 128 P
constexpr int ROWS = BATCH * L;         // 6400
constexpr size_t ALPHA_OFF = 0;
constexpr size_t H_OFF = (size_t)ROWS * NUM_D;        // 204800
constexpr size_t C_OFF = H_OFF + (size_t)ROWS * V;    // 1024000

__device__ inline u16 f2bf(float f) {
  __hip_bfloat16 h = __float2bfloat16(f);
  return __builtin_bit_cast(u16, h);
}
__device__ inline float bf2f(u16 u) { u32 x = ((u32)u) << 16; return __builtin_bit_cast(float, x); }

// convert 32 contiguous f32 -> 32 bf16 (dst 8B-aligned)
__device__ inline void cvt32(const float* __restrict__ src, u16* __restrict__ dst) {
#pragma unroll
  for (int j0 = 0; j0 < 32; j0 += 4) {
    const f32x4 v = *(const f32x4*)(src + j0);
    ushort4 s;
    s.x = f2bf(v[0]); s.y = f2bf(v[1]); s.z = f2bf(v[2]); s.w = f2bf(v[3]);
    *(ushort4*)(dst + j0) = s;
  }
}
// load 8 contiguous f32 -> bf16 MFMA fragment
__device__ inline short8 ldfrag(const float* __restrict__ p) {
  const f32x4 a = *(const f32x4*)p, b = *(const f32x4*)(p + 4);
  short8 s;
  s[0] = (short)f2bf(a[0]); s[1] = (short)f2bf(a[1]);
  s[2] = (short)f2bf(a[2]); s[3] = (short)f2bf(a[3]);
  s[4] = (short)f2bf(b[0]); s[5] = (short)f2bf(b[1]);
  s[6] = (short)f2bf(b[2]); s[7] = (short)f2bf(b[3]);
  return s;
}

// ---------------------------------------------------------------------------
// K1: Q[row, 0:384] = gru_in @ W_ih^T + b_ih ; Q[row, 384:512] = P (mem MLP)
// ---------------------------------------------------------------------------
__global__ __launch_bounds__(256) void k1(
    const int* __restrict__ c_seq, const int* __restrict__ d_seq,
    const float* __restrict__ r_seq, const float* __restrict__ X,
    const float* __restrict__ v_r, const float* __restrict__ W_ih,
    const float* __restrict__ W2a, const float* __restrict__ b_ih,
    const float* __restrict__ b2a, float* __restrict__ Qout)
{
  __shared__ __align__(16) u16 Als[64][144];
  __shared__ __align__(16) u16 Bls[64][144];
  const int tid = threadIdx.x;
  const int mt = blockIdx.x, nt = blockIdx.y;
  const int lane = tid & 63, w = tid >> 6;
  const int q = lane >> 4, m = lane & 15;

  f32x4 acc[4];
#pragma unroll
  for (int i = 0; i < 4; ++i) acc[i] = (f32x4)0.0f;

  const int r0 = tid >> 2;          // 0..63 staged row
  const int kc = (tid & 3) * 32;    // k chunk
  const int rowg = mt * 64 + r0;    // global (b,t) row
  const int gcolB = nt * 64 + r0;   // global output col staged as B row

  for (int s = 0; s < 2; ++s) {     // two K-stages of 128
    if (s) __syncthreads();
    if (s == 0) {
      const int idx = c_seq[rowg] + NUM_C * d_seq[rowg];
      cvt32(X + (size_t)idx * V + kc, &Als[r0][kc]);
    } else {
      const float rv = r_seq[rowg];
#pragma unroll
      for (int j0 = 0; j0 < 32; j0 += 4) {
        const f32x4 v = *(const f32x4*)(v_r + kc + j0);
        ushort4 sv;
        sv.x = f2bf(rv * v[0]); sv.y = f2bf(rv * v[1]);
        sv.z = f2bf(rv * v[2]); sv.w = f2bf(rv * v[3]);
        *(ushort4*)&Als[r0][kc + j0] = sv;
      }
    }
    {
      const float* src = (gcolB < G3)
        ? (W_ih + (size_t)gcolB * 256 + s * 128 + kc)
        : (W2a + (size_t)(gcolB - G3) * G3 + V + s * 128 + kc);
      cvt32(src, &Bls[r0][kc]);
    }
    __syncthreads();
#pragma unroll
    for (int c = 0; c < 4; ++c) {
      const short8 af = *(const short8*)&Als[w * 16 + m][32 * c + 8 * q];
#pragma unroll
      for (int i = 0; i < 4; ++i) {
        const short8 bf = *(const short8*)&Bls[i * 16 + m][32 * c + 8 * q];
        acc[i] = __builtin_amdgcn_mfma_f32_16x16x32_bf16(af, bf, acc[i], 0, 0, 0);
      }
    }
  }
#pragma unroll
  for (int i = 0; i < 4; ++i) {
    const int col = nt * 64 + i * 16 + m;
    const float bias = (col < G3) ? b_ih[col] : b2a[col - G3];
#pragma unroll
    for (int r = 0; r < 4; ++r) {
      const int rowo = mt * 64 + w * 16 + q * 4 + r;
      Qout[(size_t)rowo * KQ + col] = acc[i][r] + bias;
    }
  }
}

// ---------------------------------------------------------------------------
// K2: blocks 0..31 = GRU per batch ; blocks 32..63 = memory scan per batch
// Outputs are f32. Scan writes new_c directly into final C_seq cells.
// ---------------------------------------------------------------------------
union ShK2 {
  struct { u16 h_bf[2][V]; float h_f[2][V]; } g;
  struct { float C[NUM_C * NUM_D]; int cb[L]; int db[L]; float u[V]; } s;
};

__global__ __launch_bounds__(256) void k2(
    const int* __restrict__ c_seq, const int* __restrict__ d_seq,
    const float* __restrict__ W_hh, const float* __restrict__ b_hh,
    const float* __restrict__ W2a, const float* __restrict__ v_beta,
    const float* __restrict__ W2b, const float* __restrict__ b2b,
    const float* __restrict__ Q, float* __restrict__ out)
{
  __shared__ __align__(16) ShK2 sh;
  const int tid = threadIdx.x;
  const int l = tid & 63, w = tid >> 6, q = l >> 4, m = l & 15;

  if (blockIdx.x < 32) {
    // ---------------- GRU ----------------
    const int b = blockIdx.x;
    if (tid < V) { sh.g.h_bf[0][tid] = 0; sh.g.h_f[0][tid] = 0.f; }
    __syncthreads();
    // wave w owns tiles {w,w+4,...,w+20}: i=0,1 -> r ; 2,3 -> z ; 4,5 -> n
    short8 wf[6][4];
    float bhh[6]; int gcol[6];
#pragma unroll
    for (int i = 0; i < 6; ++i) {
      const int g = (w + 4 * i) * 16 + m;
      gcol[i] = g;
      bhh[i] = b_hh[g];
#pragma unroll
      for (int c = 0; c < 4; ++c)
        wf[i][c] = ldfrag(W_hh + (size_t)g * V + 32 * c + 8 * q);
    }
    const float* Qb = Q + (size_t)b * L * KQ;
    float* outh = out + H_OFF + (size_t)b * L * V;
    for (int t = 0; t < L; ++t) {
      const int rs = t & 1, wsl = rs ^ 1;
      short8 af[4];
#pragma unroll
      for (int c = 0; c < 4; ++c)
        af[c] = *(const short8*)&sh.g.h_bf[rs][32 * c + 8 * q];
      float gxv[6];
      const float* Qr = Qb + (size_t)t * KQ;
#pragma unroll
      for (int i = 0; i < 6; ++i) gxv[i] = Qr[gcol[i]];
      f32x4 acc[6];
#pragma unroll
      for (int i = 0; i < 6; ++i) acc[i] = (f32x4)0.0f;
#pragma unroll
      for (int c = 0; c < 4; ++c)
#pragma unroll
        for (int i = 0; i < 6; ++i)
          acc[i] = __builtin_amdgcn_mfma_f32_16x16x32_bf16(af[c], wf[i][c], acc[i], 0, 0, 0);
      float hnew[2];
#pragma unroll
      for (int s = 0; s < 2; ++s) {
        const int v = s * 64 + 16 * w + m;
        const float hold = sh.g.h_f[rs][v];
        const float xr = gxv[0 + s] + acc[0 + s][0] + bhh[0 + s];
        const float xz = gxv[2 + s] + acc[2 + s][0] + bhh[2 + s];
        const float ghn = acc[4 + s][0] + bhh[4 + s];
        const float r = 1.f / (1.f + __expf(-xr));
        const float z = 1.f / (1.f + __expf(-xz));
        const float xn = gxv[4 + s] + r * ghn;
        const float e = __expf(2.f * xn);
        const float n = 1.f - 2.f / (e + 1.f);     // tanh(xn)
        hnew[s] = (1.f - z) * n + z * hold;
      }
      if (q == 0) {
#pragma unroll
        for (int s = 0; s < 2; ++s) {
          const int v = s * 64 + 16 * w + m;
          sh.g.h_f[wsl][v] = hnew[s];
          sh.g.h_bf[wsl][v] = f2bf(hnew[s]);
          outh[(size_t)t * V + v] = hnew[s];
        }
      }
      __syncthreads();
    }
  } else {
    // ---------------- memory scan (single wave, no barriers in loop) -------
    const int b = blockIdx.x - 32;
    for (int i = tid; i < NUM_C * NUM_D; i += 256) sh.s.C[i] = 0.f;
    if (tid < L) { sh.s.cb[tid] = c_seq[b * L + tid]; sh.s.db[tid] = d_seq[b * L + tid]; }
    if (tid < V) {
      float a = 0.f;
      const float* wr = W2a + (size_t)tid * G3;
      for (int k = 0; k < V; ++k) a += wr[k] * v_beta[k];
      sh.s.u[tid] = a;   // u = W2a[:, :V] @ v_beta
    }
    __syncthreads();
    if (tid >= 64) return;
    float ureg[4][8];
#pragma unroll
    for (int c = 0; c < 4; ++c)
#pragma unroll
      for (int j = 0; j < 8; ++j) ureg[c][j] = sh.s.u[32 * c + 8 * q + j];
    short8 wbf[2][4];
    float bb[2];
#pragma unroll
    for (int tt = 0; tt < 2; ++tt) {
#pragma unroll
      for (int c = 0; c < 4; ++c)
        wbf[tt][c] = ldfrag(W2b + (size_t)(tt * 16 + m) * V + 32 * c + 8 * q);
      bb[tt] = b2b[tt * 16 + m];
    }
    const float* Pb = Q + (size_t)b * L * KQ + G3;
    float* outc = out + C_OFF + (size_t)b * L * (NUM_C * NUM_D);
    f32x4 pcur[4][2];
#pragma unroll
    for (int c = 0; c < 4; ++c) {
      pcur[c][0] = *(const f32x4*)(Pb + 32 * c + 8 * q);
      pcur[c][1] = *(const f32x4*)(Pb + 32 * c + 8 * q + 4);
    }
    for (int t = 0; t < L; ++t) {
      const int ct = sh.s.cb[t], dt = sh.s.db[t];
      const float beta = sh.s.C[ct * NUM_D + dt];
      short8 af[4];
#pragma unroll
      for (int c = 0; c < 4; ++c) {
        short8 a;
#pragma unroll
        for (int j = 0; j < 8; ++j) {
          const float p = (j < 4) ? pcur[c][0][j] : pcur[c][1][j - 4];
          const float hv = fmaxf(beta * ureg[c][j] + p, 0.f);
          a[j] = (short)f2bf(hv);
        }
        af[c] = a;
      }
      const int tn = (t + 1 < L) ? t + 1 : t;   // prefetch next P
      const float* Pn = Pb + (size_t)tn * KQ;
#pragma unroll
      for (int c = 0; c < 4; ++c) {
        pcur[c][0] = *(const f32x4*)(Pn + 32 * c + 8 * q);
        pcur[c][1] = *(const f32x4*)(Pn + 32 * c + 8 * q + 4);
      }
      f32x4 a0 = (f32x4)0.0f, a1 = (f32x4)0.0f;
#pragma unroll
      for (int c = 0; c < 4; ++c) {
        a0 = __builtin_amdgcn_mfma_f32_16x16x32_bf16(af[c], wbf[0][c], a0, 0, 0, 0);
        a1 = __builtin_amdgcn_mfma_f32_16x16x32_bf16(af[c], wbf[1][c], a1, 0, 0, 0);
      }
      const float n0 = a0[0] + bb[0], n1 = a1[0] + bb[1];
      if (q == 0) {
        sh.s.C[ct * NUM_D + m] = n0;
        sh.s.C[ct * NUM_D + 16 + m] = n1;
        float* oc = outc + (size_t)t * (NUM_C * NUM_D) + ct * NUM_D;
        oc[m] = n0;
        oc[16 + m] = n1;
      }
    }
  }
}

// ---------------------------------------------------------------------------
// K3: blocks 0..255 = C_seq in-place forward-fill ; 256..355 = alpha GEMM
// ---------------------------------------------------------------------------
union ShK3 {
  struct { int cb[L]; } f;
  struct { u16 hls[64][144]; u16 hid[64][144]; } a;
};

__global__ __launch_bounds__(256) void k3(
    const int* __restrict__ c_seq, const float* __restrict__ W1a,
    const float* __restrict__ b1a, const float* __restrict__ W1b,
    const float* __restrict__ b1b, float* __restrict__ out)
{
  __shared__ __align__(16) ShK3 sh;
  const int tid = threadIdx.x;
  if (blockIdx.x < 256) {
    const int blk = blockIdx.x;
    const int b = blk >> 3, cbase = (blk & 7) * 32;
    if (tid < L) sh.f.cb[tid] = c_seq[b * L + tid];
    __syncthreads();
    const int cl = tid >> 3, dq = (tid & 7) * 4;
    const int myc = cbase + cl;
    float* base = out + C_OFF + (size_t)b * L * (NUM_C * NUM_D) + (size_t)myc * NUM_D + dq;
    f32x4 cur = (f32x4)0.0f;
    for (int t = 0; t < L; ++t) {
      if (sh.f.cb[t] == myc) cur = *(const f32x4*)base;   // k2 already wrote it
      else *(f32x4*)base = cur;                           // carry forward
      base += NUM_C * NUM_D;
    }
  } else {
    const int ab = blockIdx.x - 256;    // 0..99, rows [ab*64, ab*64+64)
    const int l = tid & 63, w = tid >> 6, q = l >> 4, m = l & 15;
    {
      const int r0 = tid >> 2, kc = (tid & 3) * 32;
      cvt32(out + H_OFF + (size_t)(ab * 64 + r0) * V + kc, &sh.a.hls[r0][kc]);
    }
    __syncthreads();
    f32x4 acc1[8];
#pragma unroll
    for (int i = 0; i < 8; ++i) acc1[i] = (f32x4)0.0f;
#pragma unroll
    for (int c = 0; c < 4; ++c) {
      const short8 af = *(const short8*)&sh.a.hls[w * 16 + m][32 * c + 8 * q];
#pragma unroll
      for (int i = 0; i < 8; ++i) {
        const short8 bf = ldfrag(W1a + (size_t)(i * 16 + m) * V + 32 * c + 8 * q);
        acc1[i] = __builtin_amdgcn_mfma_f32_16x16x32_bf16(af, bf, acc1[i], 0, 0, 0);
      }
    }
#pragma unroll
    for (int i = 0; i < 8; ++i) {
      const int col = i * 16 + m;
      const float bias = b1a[col];
#pragma unroll
      for (int r = 0; r < 4; ++r)
        sh.a.hid[w * 16 + q * 4 + r][col] = f2bf(fmaxf(acc1[i][r] + bias, 0.f));
    }
    __syncthreads();
    f32x4 acc2[2];
    acc2[0] = (f32x4)0.0f; acc2[1] = (f32x4)0.0f;
#pragma unroll
    for (int c = 0; c < 4; ++c) {
      const short8 af = *(const short8*)&sh.a.hid[w * 16 + m][32 * c + 8 * q];
#pragma unroll
      for (int tt = 0; tt < 2; ++tt) {
        const short8 bf = ldfrag(W1b + (size_t)(tt * 16 + m) * V + 32 * c + 8 * q);
        acc2[tt] = __builtin_amdgcn_mfma_f32_16x16x32_bf16(af, bf, acc2[tt], 0, 0, 0);
      }
    }
#pragma unroll
    for (int tt = 0; tt < 2; ++tt) {
      const int col = tt * 16 + m;
      const float bias = b1b[col];
#pragma unroll
      for (int r = 0; r < 4; ++r) {
        const int row = ab * 64 + w * 16 + q * 4 + r;
        out[ALPHA_OFF + (size_t)row * NUM_D + col] = acc2[tt][r] + bias;
      }
    }
  }
}

extern "C" void kernel_launch(void* const* d_in, const int* in_sizes, int n_in,
                              void* d_out, int out_size, void* d_ws, size_t ws_size,
                              hipStream_t stream) {
  const int*   c_seq  = (const int*)d_in[0];
  const int*   d_seq  = (const int*)d_in[1];
  const float* r_seq  = (const float*)d_in[2];
  const float* X      = (const float*)d_in[3];
  const float* v_r    = (const float*)d_in[4];
  const float* v_beta = (const float*)d_in[5];
  const float* W_ih   = (const float*)d_in[6];
  const float* W_hh   = (const float*)d_in[7];
  const float* b_ih   = (const float*)d_in[8];
  const float* b_hh   = (const float*)d_in[9];
  const float* W1a    = (const float*)d_in[10];
  const float* b1a    = (const float*)d_in[11];
  const float* W1b    = (const float*)d_in[12];
  const float* b1b    = (const float*)d_in[13];
  const float* W2a    = (const float*)d_in[14];
  const float* b2a    = (const float*)d_in[15];
  const float* W2b    = (const float*)d_in[16];
  const float* b2b    = (const float*)d_in[17];
  float* out = (float*)d_out;
  float* Q = (float*)d_ws;

  k1<<<dim3(100, 8), 256, 0, stream>>>(c_seq, d_seq, r_seq, X, v_r, W_ih, W2a, b_ih, b2a, Q);
  k2<<<64, 256, 0, stream>>>(c_seq, d_seq, W_hh, b_hh, W2a, v_beta, W2b, b2b, Q, out);
  k3<<<356, 256, 0, stream>>>(c_seq, W1a, b1a, W1b, b1b, out);
}

// Round 5
// 399.271 us; speedup vs baseline: 1.1697x; 1.1697x over previous
//
#include <hip/hip_runtime.h>
#include <hip/hip_bf16.h>

typedef unsigned short u16;
typedef unsigned int u32;
typedef short short8 __attribute__((ext_vector_type(8)));
typedef float f32x4 __attribute__((ext_vector_type(4)));

constexpr int BATCH = 32, L = 200, NUM_C = 256, NUM_D = 32, V = 128;
constexpr int G3 = 384;                 // 3*V
constexpr int KQ = 512;                 // Q row: 384 gx | 128 P
constexpr int ROWS = BATCH * L;         // 6400
constexpr size_t ALPHA_OFF = 0;
constexpr size_t H_OFF = (size_t)ROWS * NUM_D;        // 204800
constexpr size_t C_OFF = H_OFF + (size_t)ROWS * V;    // 1024000

__device__ inline u16 f2bf(float f) {
  __hip_bfloat16 h = __float2bfloat16(f);
  return __builtin_bit_cast(u16, h);
}
__device__ inline float bf2f(u16 u) { u32 x = ((u32)u) << 16; return __builtin_bit_cast(float, x); }

// convert 32 contiguous f32 -> 32 bf16 (dst 8B-aligned)
__device__ inline void cvt32(const float* __restrict__ src, u16* __restrict__ dst) {
#pragma unroll
  for (int j0 = 0; j0 < 32; j0 += 4) {
    const f32x4 v = *(const f32x4*)(src + j0);
    ushort4 s;
    s.x = f2bf(v[0]); s.y = f2bf(v[1]); s.z = f2bf(v[2]); s.w = f2bf(v[3]);
    *(ushort4*)(dst + j0) = s;
  }
}
// load 8 contiguous f32 -> bf16 MFMA fragment
__device__ inline short8 ldfrag(const float* __restrict__ p) {
  const f32x4 a = *(const f32x4*)p, b = *(const f32x4*)(p + 4);
  short8 s;
  s[0] = (short)f2bf(a[0]); s[1] = (short)f2bf(a[1]);
  s[2] = (short)f2bf(a[2]); s[3] = (short)f2bf(a[3]);
  s[4] = (short)f2bf(b[0]); s[5] = (short)f2bf(b[1]);
  s[6] = (short)f2bf(b[2]); s[7] = (short)f2bf(b[3]);
  return s;
}

// ---------------------------------------------------------------------------
// K1: Q[row, 0:384] = gru_in @ W_ih^T + b_ih ; Q[row, 384:512] = P (mem MLP)
// ---------------------------------------------------------------------------
__global__ __launch_bounds__(256) void k1(
    const int* __restrict__ c_seq, const int* __restrict__ d_seq,
    const float* __restrict__ r_seq, const float* __restrict__ X,
    const float* __restrict__ v_r, const float* __restrict__ W_ih,
    const float* __restrict__ W2a, const float* __restrict__ b_ih,
    const float* __restrict__ b2a, float* __restrict__ Qout)
{
  __shared__ __align__(16) u16 Als[64][144];
  __shared__ __align__(16) u16 Bls[64][144];
  const int tid = threadIdx.x;
  const int mt = blockIdx.x, nt = blockIdx.y;
  const int lane = tid & 63, w = tid >> 6;
  const int q = lane >> 4, m = lane & 15;

  f32x4 acc[4];
#pragma unroll
  for (int i = 0; i < 4; ++i) acc[i] = (f32x4)0.0f;

  const int r0 = tid >> 2;          // 0..63 staged row
  const int kc = (tid & 3) * 32;    // k chunk
  const int rowg = mt * 64 + r0;    // global (b,t) row
  const int gcolB = nt * 64 + r0;   // global output col staged as B row

  for (int s = 0; s < 2; ++s) {     // two K-stages of 128
    if (s) __syncthreads();
    if (s == 0) {
      const int idx = c_seq[rowg] + NUM_C * d_seq[rowg];
      cvt32(X + (size_t)idx * V + kc, &Als[r0][kc]);
    } else {
      const float rv = r_seq[rowg];
#pragma unroll
      for (int j0 = 0; j0 < 32; j0 += 4) {
        const f32x4 v = *(const f32x4*)(v_r + kc + j0);
        ushort4 sv;
        sv.x = f2bf(rv * v[0]); sv.y = f2bf(rv * v[1]);
        sv.z = f2bf(rv * v[2]); sv.w = f2bf(rv * v[3]);
        *(ushort4*)&Als[r0][kc + j0] = sv;
      }
    }
    {
      const float* src = (gcolB < G3)
        ? (W_ih + (size_t)gcolB * 256 + s * 128 + kc)
        : (W2a + (size_t)(gcolB - G3) * G3 + V + s * 128 + kc);
      cvt32(src, &Bls[r0][kc]);
    }
    __syncthreads();
#pragma unroll
    for (int c = 0; c < 4; ++c) {
      const short8 af = *(const short8*)&Als[w * 16 + m][32 * c + 8 * q];
#pragma unroll
      for (int i = 0; i < 4; ++i) {
        const short8 bf = *(const short8*)&Bls[i * 16 + m][32 * c + 8 * q];
        acc[i] = __builtin_amdgcn_mfma_f32_16x16x32_bf16(af, bf, acc[i], 0, 0, 0);
      }
    }
  }
#pragma unroll
  for (int i = 0; i < 4; ++i) {
    const int col = nt * 64 + i * 16 + m;
    const float bias = (col < G3) ? b_ih[col] : b2a[col - G3];
#pragma unroll
    for (int r = 0; r < 4; ++r) {
      const int rowo = mt * 64 + w * 16 + q * 4 + r;
      Qout[(size_t)rowo * KQ + col] = acc[i][r] + bias;
    }
  }
}

// ---------------------------------------------------------------------------
// K2: blocks 0..31 = GRU per batch ; blocks 32..63 = memory scan per batch
// GRU: Q-row prefetch (t+1) + deferred global h store + register hold.
// Scan: early beta prefetch after C write.
// ---------------------------------------------------------------------------
union ShK2 {
  struct { u16 h_bf[2][V]; } g;
  struct { float C[NUM_C * NUM_D]; int cb[L]; int db[L]; float u[V]; } s;
};

__global__ __launch_bounds__(256) void k2(
    const int* __restrict__ c_seq, const int* __restrict__ d_seq,
    const float* __restrict__ W_hh, const float* __restrict__ b_hh,
    const float* __restrict__ W2a, const float* __restrict__ v_beta,
    const float* __restrict__ W2b, const float* __restrict__ b2b,
    const float* __restrict__ Q, float* __restrict__ out)
{
  __shared__ __align__(16) ShK2 sh;
  const int tid = threadIdx.x;
  const int l = tid & 63, w = tid >> 6, q = l >> 4, m = l & 15;

  if (blockIdx.x < 32) {
    // ---------------- GRU ----------------
    const int b = blockIdx.x;
    if (tid < V) sh.g.h_bf[0][tid] = 0;
    __syncthreads();
    // wave w owns tiles {w,w+4,...,w+20}: i=0,1 -> r ; 2,3 -> z ; 4,5 -> n
    short8 wf[6][4];
    float bhh[6]; int gcol[6];
#pragma unroll
    for (int i = 0; i < 6; ++i) {
      const int g = (w + 4 * i) * 16 + m;
      gcol[i] = g;
      bhh[i] = b_hh[g];
#pragma unroll
      for (int c = 0; c < 4; ++c)
        wf[i][c] = ldfrag(W_hh + (size_t)g * V + 32 * c + 8 * q);
    }
    const float* Qb = Q + (size_t)b * L * KQ;
    float* outh = out + H_OFF + (size_t)b * L * V;
    const int vi0 = 16 * w + m, vi1 = 64 + 16 * w + m;
    float hold[2] = {0.f, 0.f};       // valid for q==0 lanes (the writers)
    float hst[2] = {0.f, 0.f};        // previous step's h, stored next iter
    float gxv[6];
#pragma unroll
    for (int i = 0; i < 6; ++i) gxv[i] = Qb[gcol[i]];   // t=0 preload
    for (int t = 0; t < L; ++t) {
      const int rs = t & 1, wsl = rs ^ 1;
      // prefetch next step's gate-input row (hides HBM/L3 latency)
      float gxn[6];
      const float* Qn = Qb + (size_t)((t + 1 < L) ? t + 1 : t) * KQ;
#pragma unroll
      for (int i = 0; i < 6; ++i) gxn[i] = Qn[gcol[i]];
      // deferred global store of h(t-1): full iteration to retire before drain
      if (t > 0 && q == 0) {
        outh[(size_t)(t - 1) * V + vi0] = hst[0];
        outh[(size_t)(t - 1) * V + vi1] = hst[1];
      }
      short8 af[4];
#pragma unroll
      for (int c = 0; c < 4; ++c)
        af[c] = *(const short8*)&sh.g.h_bf[rs][32 * c + 8 * q];
      f32x4 acc[6];
#pragma unroll
      for (int i = 0; i < 6; ++i) acc[i] = (f32x4)0.0f;
#pragma unroll
      for (int c = 0; c < 4; ++c)
#pragma unroll
        for (int i = 0; i < 6; ++i)
          acc[i] = __builtin_amdgcn_mfma_f32_16x16x32_bf16(af[c], wf[i][c], acc[i], 0, 0, 0);
      float hnew[2];
#pragma unroll
      for (int s = 0; s < 2; ++s) {
        const float xr = gxv[0 + s] + acc[0 + s][0] + bhh[0 + s];
        const float xz = gxv[2 + s] + acc[2 + s][0] + bhh[2 + s];
        const float ghn = acc[4 + s][0] + bhh[4 + s];
        const float r = 1.f / (1.f + __expf(-xr));
        const float z = 1.f / (1.f + __expf(-xz));
        const float xn = gxv[4 + s] + r * ghn;
        const float e = __expf(2.f * xn);
        const float n = 1.f - 2.f / (e + 1.f);     // tanh(xn)
        hnew[s] = (1.f - z) * n + z * hold[s];
      }
      if (q == 0) {
        sh.g.h_bf[wsl][vi0] = f2bf(hnew[0]);
        sh.g.h_bf[wsl][vi1] = f2bf(hnew[1]);
      }
      hold[0] = hnew[0]; hold[1] = hnew[1];
      hst[0] = hnew[0]; hst[1] = hnew[1];
      __syncthreads();
#pragma unroll
      for (int i = 0; i < 6; ++i) gxv[i] = gxn[i];
    }
    if (q == 0) {
      outh[(size_t)(L - 1) * V + vi0] = hst[0];
      outh[(size_t)(L - 1) * V + vi1] = hst[1];
    }
  } else {
    // ---------------- memory scan (single wave, no barriers in loop) -------
    const int b = blockIdx.x - 32;
    for (int i = tid; i < NUM_C * NUM_D; i += 256) sh.s.C[i] = 0.f;
    if (tid < L) { sh.s.cb[tid] = c_seq[b * L + tid]; sh.s.db[tid] = d_seq[b * L + tid]; }
    if (tid < V) {
      float a = 0.f;
      const float* wr = W2a + (size_t)tid * G3;
      for (int k = 0; k < V; ++k) a += wr[k] * v_beta[k];
      sh.s.u[tid] = a;   // u = W2a[:, :V] @ v_beta
    }
    __syncthreads();
    if (tid >= 64) return;
    float ureg[4][8];
#pragma unroll
    for (int c = 0; c < 4; ++c)
#pragma unroll
      for (int j = 0; j < 8; ++j) ureg[c][j] = sh.s.u[32 * c + 8 * q + j];
    short8 wbf[2][4];
    float bb[2];
#pragma unroll
    for (int tt = 0; tt < 2; ++tt) {
#pragma unroll
      for (int c = 0; c < 4; ++c)
        wbf[tt][c] = ldfrag(W2b + (size_t)(tt * 16 + m) * V + 32 * c + 8 * q);
      bb[tt] = b2b[tt * 16 + m];
    }
    const float* Pb = Q + (size_t)b * L * KQ + G3;
    float* outc = out + C_OFF + (size_t)b * L * (NUM_C * NUM_D);
    f32x4 pcur[4][2];
#pragma unroll
    for (int c = 0; c < 4; ++c) {
      pcur[c][0] = *(const f32x4*)(Pb + 32 * c + 8 * q);
      pcur[c][1] = *(const f32x4*)(Pb + 32 * c + 8 * q + 4);
    }
    float beta = 0.f;                 // C starts at zero
    for (int t = 0; t < L; ++t) {
      const int ct = sh.s.cb[t];
      short8 af[4];
#pragma unroll
      for (int c = 0; c < 4; ++c) {
        short8 a;
#pragma unroll
        for (int j = 0; j < 8; ++j) {
          const float p = (j < 4) ? pcur[c][0][j] : pcur[c][1][j - 4];
          const float hv = fmaxf(beta * ureg[c][j] + p, 0.f);
          a[j] = (short)f2bf(hv);
        }
        af[c] = a;
      }
      const int tn = (t + 1 < L) ? t + 1 : t;   // prefetch next P
      const float* Pn = Pb + (size_t)tn * KQ;
#pragma unroll
      for (int c = 0; c < 4; ++c) {
        pcur[c][0] = *(const f32x4*)(Pn + 32 * c + 8 * q);
        pcur[c][1] = *(const f32x4*)(Pn + 32 * c + 8 * q + 4);
      }
      f32x4 a0 = (f32x4)0.0f, a1 = (f32x4)0.0f;
#pragma unroll
      for (int c = 0; c < 4; ++c) {
        a0 = __builtin_amdgcn_mfma_f32_16x16x32_bf16(af[c], wbf[0][c], a0, 0, 0, 0);
        a1 = __builtin_amdgcn_mfma_f32_16x16x32_bf16(af[c], wbf[1][c], a1, 0, 0, 0);
      }
      const float n0 = a0[0] + bb[0], n1 = a1[0] + bb[1];
      if (q == 0) {
        sh.s.C[ct * NUM_D + m] = n0;
        sh.s.C[ct * NUM_D + 16 + m] = n1;
        float* oc = outc + (size_t)t * (NUM_C * NUM_D) + ct * NUM_D;
        oc[m] = n0;
        oc[16 + m] = n1;
      }
      // early beta prefetch for t+1 (after the write, drain LDS first)
      __builtin_amdgcn_s_waitcnt(0xc07f);   // lgkmcnt(0)
      if (t + 1 < L)
        beta = sh.s.C[sh.s.cb[t + 1] * NUM_D + sh.s.db[t + 1]];
    }
  }
}

// ---------------------------------------------------------------------------
// K3: blocks 0..255 = C_seq forward-fill (LDS-staged) ; 256..355 = alpha GEMM
// ---------------------------------------------------------------------------
union ShK3 {
  struct { int cb[L]; float stage[L][NUM_D]; } f;
  struct { u16 hls[64][144]; u16 hid[64][144]; } a;
};

__global__ __launch_bounds__(256) void k3(
    const int* __restrict__ c_seq, const float* __restrict__ W1a,
    const float* __restrict__ b1a, const float* __restrict__ W1b,
    const float* __restrict__ b1b, float* __restrict__ out)
{
  __shared__ __align__(16) ShK3 sh;
  const int tid = threadIdx.x;
  if (blockIdx.x < 256) {
    const int blk = blockIdx.x;
    const int b = blk >> 3, cbase = (blk & 7) * 32;
    if (tid < L) sh.f.cb[tid] = c_seq[b * L + tid];
    __syncthreads();
    // phase A: stage this block's update rows (parallel independent loads)
    if (tid < L) {
      const int c = sh.f.cb[tid];
      if (c >= cbase && c < cbase + 32) {
        const float* src = out + C_OFF + ((size_t)b * L + tid) * (NUM_C * NUM_D) + (size_t)c * NUM_D;
#pragma unroll
        for (int j = 0; j < 8; ++j)
          *(f32x4*)&sh.f.stage[tid][j * 4] = *(const f32x4*)(src + j * 4);
      }
    }
    __syncthreads();
    // phase B: pure store loop, no dependent global loads
    const int cl = tid >> 3, dq = (tid & 7) * 4;
    const int myc = cbase + cl;
    float* base = out + C_OFF + (size_t)b * L * (NUM_C * NUM_D) + (size_t)myc * NUM_D + dq;
    f32x4 cur = (f32x4)0.0f;
    for (int t = 0; t < L; ++t) {
      if (sh.f.cb[t] == myc) cur = *(const f32x4*)&sh.f.stage[t][dq];
      *(f32x4*)base = cur;
      base += NUM_C * NUM_D;
    }
  } else {
    const int ab = blockIdx.x - 256;    // 0..99, rows [ab*64, ab*64+64)
    const int l = tid & 63, w = tid >> 6, q = l >> 4, m = l & 15;
    {
      const int r0 = tid >> 2, kc = (tid & 3) * 32;
      cvt32(out + H_OFF + (size_t)(ab * 64 + r0) * V + kc, &sh.a.hls[r0][kc]);
    }
    __syncthreads();
    f32x4 acc1[8];
#pragma unroll
    for (int i = 0; i < 8; ++i) acc1[i] = (f32x4)0.0f;
#pragma unroll
    for (int c = 0; c < 4; ++c) {
      const short8 af = *(const short8*)&sh.a.hls[w * 16 + m][32 * c + 8 * q];
#pragma unroll
      for (int i = 0; i < 8; ++i) {
        const short8 bf = ldfrag(W1a + (size_t)(i * 16 + m) * V + 32 * c + 8 * q);
        acc1[i] = __builtin_amdgcn_mfma_f32_16x16x32_bf16(af, bf, acc1[i], 0, 0, 0);
      }
    }
#pragma unroll
    for (int i = 0; i < 8; ++i) {
      const int col = i * 16 + m;
      const float bias = b1a[col];
#pragma unroll
      for (int r = 0; r < 4; ++r)
        sh.a.hid[w * 16 + q * 4 + r][col] = f2bf(fmaxf(acc1[i][r] + bias, 0.f));
    }
    __syncthreads();
    f32x4 acc2[2];
    acc2[0] = (f32x4)0.0f; acc2[1] = (f32x4)0.0f;
#pragma unroll
    for (int c = 0; c < 4; ++c) {
      const short8 af = *(const short8*)&sh.a.hid[w * 16 + m][32 * c + 8 * q];
#pragma unroll
      for (int tt = 0; tt < 2; ++tt) {
        const short8 bf = ldfrag(W1b + (size_t)(tt * 16 + m) * V + 32 * c + 8 * q);
        acc2[tt] = __builtin_amdgcn_mfma_f32_16x16x32_bf16(af, bf, acc2[tt], 0, 0, 0);
      }
    }
#pragma unroll
    for (int tt = 0; tt < 2; ++tt) {
      const int col = tt * 16 + m;
      const float bias = b1b[col];
#pragma unroll
      for (int r = 0; r < 4; ++r) {
        const int row = ab * 64 + w * 16 + q * 4 + r;
        out[ALPHA_OFF + (size_t)row * NUM_D + col] = acc2[tt][r] + bias;
      }
    }
  }
}

extern "C" void kernel_launch(void* const* d_in, const int* in_sizes, int n_in,
                              void* d_out, int out_size, void* d_ws, size_t ws_size,
                              hipStream_t stream) {
  const int*   c_seq  = (const int*)d_in[0];
  const int*   d_seq  = (const int*)d_in[1];
  const float* r_seq  = (const float*)d_in[2];
  const float* X      = (const float*)d_in[3];
  const float* v_r    = (const float*)d_in[4];
  const float* v_beta = (const float*)d_in[5];
  const float* W_ih   = (const float*)d_in[6];
  const float* W_hh   = (const float*)d_in[7];
  const float* b_ih   = (const float*)d_in[8];
  const float* b_hh   = (const float*)d_in[9];
  const float* W1a    = (const float*)d_in[10];
  const float* b1a    = (const float*)d_in[11];
  const float* W1b    = (const float*)d_in[12];
  const float* b1b    = (const float*)d_in[13];
  const float* W2a    = (const float*)d_in[14];
  const float* b2a    = (const float*)d_in[15];
  const float* W2b    = (const float*)d_in[16];
  const float* b2b    = (const float*)d_in[17];
  float* out = (float*)d_out;
  float* Q = (float*)d_ws;

  k1<<<dim3(100, 8), 256, 0, stream>>>(c_seq, d_seq, r_seq, X, v_r, W_ih, W2a, b_ih, b2a, Q);
  k2<<<64, 256, 0, stream>>>(c_seq, d_seq, W_hh, b_hh, W2a, v_beta, W2b, b2b, Q, out);
  k3<<<356, 256, 0, stream>>>(c_seq, W1a, b1a, W1b, b1b, out);
}